// Round 5
// baseline (332.313 us; speedup 1.0000x reference)
//
#include <hip/hip_runtime.h>
#include <hip/hip_bf16.h>

// CausalSelfAttention: B=4, S=2048, D=1024, H=16, Dh=64. fp32 in/out, bf16 MFMA compute.
//
// Pipeline (all on `stream`):
//   1. convert_x: x fp32 -> bf16 (8192x1024)
//   2. transpose_w: Wq|Wk|Wv -> wqkvt (3072x1024 bf16, N-major), Wo -> wot
//   3. pack_bqkv: [bq|bk|bv] -> fp32 (3072)
//   4. gemm<0>: qkv = xb @ [Wq|Wk|Wv] + b  -> qk bf16 (8192x2048) + vt (B,H,Dh,S) scatter
//   5. attn: barrier-free flash attention: 1 wave/block, 32 q/wave, direct global frags
//   6. gemm<1>: out = attn @ Wo + bo       -> fp32 d_out

typedef __bf16 bf16x8 __attribute__((ext_vector_type(8)));
typedef float f32x4 __attribute__((ext_vector_type(4)));
typedef unsigned short u16;

__device__ __forceinline__ u16 f2b(float f) {
    __hip_bfloat16 h = __float2bfloat16(f);
    return __builtin_bit_cast(unsigned short, h);
}

__device__ __forceinline__ f32x4 mfma16(bf16x8 a, bf16x8 b, f32x4 c) {
    return __builtin_amdgcn_mfma_f32_16x16x32_bf16(a, b, c, 0, 0, 0);
}

typedef const __attribute__((address_space(1))) unsigned int* gas1_t;
typedef __attribute__((address_space(3))) unsigned int* las3_t;
__device__ __forceinline__ void gld16(const void* g, void* l) {
    __builtin_amdgcn_global_load_lds((gas1_t)g, (las3_t)l, 16, 0, 0);
}

// ---------------------------------------------------------------- conversions
__global__ __launch_bounds__(256) void convert_x(const float* __restrict__ x,
                                                 u16* __restrict__ xb, int n4) {
    int i = blockIdx.x * 256 + threadIdx.x;
    if (i < n4) {
        float4 v = ((const float4*)x)[i];
        ushort4 u;
        u.x = f2b(v.x); u.y = f2b(v.y); u.z = f2b(v.z); u.w = f2b(v.w);
        ((ushort4*)xb)[i] = u;
    }
}

// W (K=1024 rows, N=1024 cols) fp32 -> Wt (N,K) bf16. z selects matrix.
__global__ __launch_bounds__(256) void transpose_w(const float* __restrict__ Wq,
                                                   const float* __restrict__ Wk,
                                                   const float* __restrict__ Wv,
                                                   const float* __restrict__ Wo,
                                                   u16* __restrict__ wqkvt,
                                                   u16* __restrict__ wot) {
    const int z = blockIdx.z;
    const float* src = (z == 0) ? Wq : (z == 1) ? Wk : (z == 2) ? Wv : Wo;
    u16* dst = (z == 3) ? wot : (wqkvt + (size_t)z * 1024 * 1024);
    __shared__ float tile[32][33];
    const int tx = threadIdx.x, ty = threadIdx.y;  // block (32,8)
    const int nbase = blockIdx.x * 32, kbase = blockIdx.y * 32;
    for (int j = 0; j < 4; ++j)
        tile[ty + j * 8][tx] = src[(size_t)(kbase + ty + j * 8) * 1024 + nbase + tx];
    __syncthreads();
    for (int j = 0; j < 4; ++j)
        dst[(size_t)(nbase + ty + j * 8) * 1024 + kbase + tx] = f2b(tile[tx][ty + j * 8]);
}

__global__ __launch_bounds__(256) void pack_bqkv(const float* __restrict__ bq,
                                                 const float* __restrict__ bk,
                                                 const float* __restrict__ bv,
                                                 float* __restrict__ bqkv) {
    int i = blockIdx.x * 256 + threadIdx.x;  // 3072 total
    bqkv[i] = (i < 1024) ? bq[i] : (i < 2048) ? bk[i - 1024] : bv[i - 2048];
}

// ---------------------------------------------------------------- GEMM (m97-style)
// C(M,N) = A(M,K) @ Bt(N,K)^T + bias. 128x128 tile, BK=32, 256 thr = 4 waves.
// MODE 0: QKV-combined: cols <2048 -> bf16 row-major qk; cols >=2048 -> V^T scatter.
// MODE 1: fp32 row-major out.
template <int MODE>
__global__ __launch_bounds__(256) void gemm_bt(const u16* __restrict__ A,
                                               const u16* __restrict__ Bt,
                                               const float* __restrict__ bias,
                                               void* __restrict__ Cout,
                                               void* __restrict__ Cout2,
                                               int M, int N, int K, int ldc) {
    const int tid = threadIdx.x;
    const int l = tid & 63;
    const int w = tid >> 6;
    const int tileM = blockIdx.x * 128;
    const int tileN = blockIdx.y * 128;

    __shared__ u16 As[128 * 32];
    __shared__ u16 Bs[128 * 32];

    const int srow = l >> 2;
    const int schunk = l & 3;
    const int mrow = l & 15;
    const int g8 = (l >> 4) * 8;
    const int waveM = (w & 1) * 64;
    const int waveN = (w >> 1) * 64;

    f32x4 acc[4][4] = {};

    for (int k0 = 0; k0 < K; k0 += 32) {
        gld16(A + (size_t)(tileM + w * 32 + srow) * K + k0 + schunk * 8, &As[(w * 2) * 512]);
        gld16(A + (size_t)(tileM + w * 32 + 16 + srow) * K + k0 + schunk * 8, &As[(w * 2 + 1) * 512]);
        gld16(Bt + (size_t)(tileN + w * 32 + srow) * K + k0 + schunk * 8, &Bs[(w * 2) * 512]);
        gld16(Bt + (size_t)(tileN + w * 32 + 16 + srow) * K + k0 + schunk * 8, &Bs[(w * 2 + 1) * 512]);
        __syncthreads();

        bf16x8 af[4], bf[4];
        for (int im = 0; im < 4; ++im)
            af[im] = *(const bf16x8*)&As[(waveM + im * 16 + mrow) * 32 + g8];
        for (int in = 0; in < 4; ++in)
            bf[in] = *(const bf16x8*)&Bs[(waveN + in * 16 + mrow) * 32 + g8];
        for (int im = 0; im < 4; ++im)
            for (int in = 0; in < 4; ++in)
                acc[im][in] = mfma16(af[im], bf[in], acc[im][in]);
        __syncthreads();
    }

    // epilogue. C/D layout: row=(l>>4)*4+r, col=l&15  [m89/m91]
    const int rbase = (l >> 4) * 4;
    for (int im = 0; im < 4; ++im) {
        for (int in = 0; in < 4; ++in) {
            const int gm0 = tileM + waveM + im * 16 + rbase;
            const int gn = tileN + waveN + in * 16 + (l & 15);
            const float bv_ = bias[gn];
            if (MODE == 1) {
                float* out = (float*)Cout;
                for (int r = 0; r < 4; ++r)
                    out[(size_t)(gm0 + r) * ldc + gn] = acc[im][in][r] + bv_;
            } else if (tileN < 2048) {
                u16* out = (u16*)Cout;  // qk, row-major (token, 2048)
                for (int r = 0; r < 4; ++r)
                    out[(size_t)(gm0 + r) * 2048 + gn] = f2b(acc[im][in][r] + bv_);
            } else {
                u16* out = (u16*)Cout2;  // V^T scatter (B,H,Dh,S)
                const int b = gm0 >> 11, s0 = gm0 & 2047;
                const int gn2 = gn - 2048;
                const int h = gn2 >> 6, dh = gn2 & 63;
                ushort4 u;
                u.x = f2b(acc[im][in][0] + bv_);
                u.y = f2b(acc[im][in][1] + bv_);
                u.z = f2b(acc[im][in][2] + bv_);
                u.w = f2b(acc[im][in][3] + bv_);
                *(ushort4*)&out[((size_t)((b * 16 + h) * 64 + dh)) * 2048 + s0] = u;
            }
        }
    }
}

// ---------------------------------------------------------------- flash attention
// Barrier-free: 1 wave per block (64 thr), 32 queries/wave. All MFMA fragments
// (K, V^T, Q) are direct 16B global loads (Dh=64 makes every frag row-contiguous);
// LDS holds only the per-wave P C->A roundtrip slab (4.6 KB). No __syncthreads.
// Grid (bh=64, seg=64): linear id % 8 == bh % 8 -> one head's K/V stays on one
// XCD; 8 heads x 512 KB = 4 MB = L2-resident. s = 63-y launches big blocks first.
__global__ __launch_bounds__(64, 3) void attn_kernel(const u16* __restrict__ qk,
                                                     const u16* __restrict__ vt,
                                                     u16* __restrict__ attn) {
    const int bh = blockIdx.x;
    const int s = 63 - (int)blockIdx.y;   // 32-query segment, big-first
    const int b = bh >> 4, h = bh & 15;
    const int l = threadIdx.x & 63;
    const int q = l & 15;   // query column within group
    const int g = l >> 4;   // k-group
    const int g8 = g * 8;
    const int q0 = s * 32;

    __shared__ u16 Ps[32 * 72];  // per-wave P slab [query][key]

    // Q B-frags direct from global: Q[query=q0+c*16+q][dh=kh*32+g8..+7]
    bf16x8 qb[2][2];
    for (int c = 0; c < 2; ++c)
        for (int kh = 0; kh < 2; ++kh)
            qb[c][kh] = *(const bf16x8*)&qk[(size_t)(b * 2048 + q0 + c * 16 + q) * 2048 +
                                            h * 64 + kh * 32 + g8];

    float m2[2] = {-1e30f, -1e30f}, li[2] = {0.f, 0.f};
    f32x4 o[2][4] = {};
    const int tmax = s >> 1;  // tiles 0..tmax cover keys 0..q0+31(+pad)
    const u16* kbase = qk + (size_t)(b * 2048) * 2048 + 1024 + h * 64;  // +key*2048+kh*32+g8
    const u16* vbase = vt + (size_t)(bh * 64) * 2048;                   // +dh*2048+key
    const float SCALE_L2E = 0.125f * 1.4426950408889634f;

    for (int t = 0; t <= tmax; ++t) {
        const int kv0 = t * 64;
        // K A-frags: K[key=kv0+cb*16+q][dh] — needed first
        bf16x8 ka[4][2];
        for (int cb = 0; cb < 4; ++cb)
            for (int kh = 0; kh < 2; ++kh)
                ka[cb][kh] = *(const bf16x8*)&kbase[(size_t)(kv0 + cb * 16 + q) * 2048 +
                                                   kh * 32 + g8];
        // V A-frags: V^T[dh=cb*16+q][key=kv0+kh*32+g8..] — issue early, used after softmax
        bf16x8 va[4][2];
        for (int cb = 0; cb < 4; ++cb)
            for (int kh = 0; kh < 2; ++kh)
                va[cb][kh] = *(const bf16x8*)&vbase[(size_t)(cb * 16 + q) * 2048 +
                                                   kv0 + kh * 32 + g8];

        // S^T = K @ Q^T
        f32x4 st[2][4] = {};
        for (int kh = 0; kh < 2; ++kh)
            for (int cb = 0; cb < 4; ++cb) {
                st[0][cb] = mfma16(ka[cb][kh], qb[0][kh], st[0][cb]);
                st[1][cb] = mfma16(ka[cb][kh], qb[1][kh], st[1][cb]);
            }

        for (int c = 0; c < 2; ++c) {
            const int qg = q0 + c * 16 + q;
            if (t == tmax) {  // only the diagonal tile has masked keys
                for (int cb = 0; cb < 4; ++cb)
                    for (int r = 0; r < 4; ++r) {
                        const int key = kv0 + cb * 16 + g * 4 + r;
                        const float xv = st[c][cb][r] * SCALE_L2E;
                        st[c][cb][r] = (key > qg) ? -1e30f : xv;
                    }
            } else {
                for (int cb = 0; cb < 4; ++cb)
                    for (int r = 0; r < 4; ++r) st[c][cb][r] *= SCALE_L2E;
            }
            float mx = st[c][0][0];
            for (int cb = 0; cb < 4; ++cb)
                for (int r = 0; r < 4; ++r) mx = fmaxf(mx, st[c][cb][r]);
            mx = fmaxf(mx, __shfl_xor(mx, 16));
            mx = fmaxf(mx, __shfl_xor(mx, 32));
            const float mnew = fmaxf(m2[c], mx);
            const float alpha = __builtin_amdgcn_exp2f(m2[c] - mnew);
            m2[c] = mnew;
            float ps = 0.f;
            for (int cb = 0; cb < 4; ++cb)
                for (int r = 0; r < 4; ++r) {
                    const float p = __builtin_amdgcn_exp2f(st[c][cb][r] - mnew);
                    st[c][cb][r] = p;
                    ps += p;
                }
            ps += __shfl_xor(ps, 16);
            ps += __shfl_xor(ps, 32);
            li[c] = li[c] * alpha + ps;
            for (int cb = 0; cb < 4; ++cb) o[c][cb] *= alpha;
            // P^T C-regs -> Ps[query][key] (r=0..3 consecutive keys -> b64)
            for (int cb = 0; cb < 4; ++cb) {
                ushort4 u;
                u.x = f2b(st[c][cb][0]); u.y = f2b(st[c][cb][1]);
                u.z = f2b(st[c][cb][2]); u.w = f2b(st[c][cb][3]);
                *(ushort4*)&Ps[(c * 16 + q) * 72 + cb * 16 + g * 4] = u;
            }
        }
        __builtin_amdgcn_s_waitcnt(0xC07F);  // lgkmcnt(0); DS in-order per wave
        // O^T += V^T @ P^T
        for (int kh = 0; kh < 2; ++kh) {
            bf16x8 pb0 = *(const bf16x8*)&Ps[(0 * 16 + q) * 72 + kh * 32 + g8];
            bf16x8 pb1 = *(const bf16x8*)&Ps[(1 * 16 + q) * 72 + kh * 32 + g8];
            for (int cb = 0; cb < 4; ++cb) {
                o[0][cb] = mfma16(va[cb][kh], pb0, o[0][cb]);
                o[1][cb] = mfma16(va[cb][kh], pb1, o[1][cb]);
            }
        }
    }

    // epilogue: attn[token][h*64+dh], dh = cb*16+g*4+r contiguous
    for (int c = 0; c < 2; ++c) {
        const float inv = 1.0f / li[c];
        const size_t tok = (size_t)(b * 2048 + q0 + c * 16 + q);
        for (int cb = 0; cb < 4; ++cb) {
            ushort4 u;
            u.x = f2b(o[c][cb][0] * inv); u.y = f2b(o[c][cb][1] * inv);
            u.z = f2b(o[c][cb][2] * inv); u.w = f2b(o[c][cb][3] * inv);
            *(ushort4*)&attn[tok * 1024 + h * 64 + cb * 16 + g * 4] = u;
        }
    }
}

// ---------------------------------------------------------------- launch
extern "C" void kernel_launch(void* const* d_in, const int* in_sizes, int n_in,
                              void* d_out, int out_size, void* d_ws, size_t ws_size,
                              hipStream_t stream) {
    const float* x  = (const float*)d_in[0];
    const float* Wq = (const float*)d_in[1];
    const float* bq = (const float*)d_in[2];
    const float* Wk = (const float*)d_in[3];
    const float* bk = (const float*)d_in[4];
    const float* Wv = (const float*)d_in[5];
    const float* bv = (const float*)d_in[6];
    const float* Wo = (const float*)d_in[7];
    const float* bo = (const float*)d_in[8];
    float* out = (float*)d_out;

    char* ws = (char*)d_ws;
    size_t off = 0;
    auto alloc = [&](size_t bytes) -> void* {
        void* p = ws + off;
        off += (bytes + 255) & ~(size_t)255;
        return p;
    };
    u16*   xb    = (u16*)alloc(8192ull * 1024 * 2);   // x bf16
    u16*   wqkvt = (u16*)alloc(3072ull * 1024 * 2);   // [Wq|Wk|Wv]^T (N,K)
    u16*   wot   = (u16*)alloc(1024ull * 1024 * 2);   // Wo^T
    float* bqkv  = (float*)alloc(3072ull * 4);
    u16*   qk    = (u16*)alloc(8192ull * 2048 * 2);   // [q|k] (token, 2048)
    u16*   vt    = (u16*)alloc(8192ull * 1024 * 2);   // V^T (B,H,Dh,S)
    u16*   attn  = (u16*)alloc(8192ull * 1024 * 2);   // attention out (token, D)

    convert_x<<<8192, 256, 0, stream>>>(x, xb, 8192 * 1024 / 4);
    transpose_w<<<dim3(32, 32, 4), dim3(32, 8), 0, stream>>>(Wq, Wk, Wv, Wo, wqkvt, wot);
    pack_bqkv<<<12, 256, 0, stream>>>(bq, bk, bv, bqkv);
    gemm_bt<0><<<dim3(64, 24), 256, 0, stream>>>(xb, wqkvt, bqkv, qk, vt, 8192, 3072, 1024, 0);
    attn_kernel<<<dim3(64, 64), 64, 0, stream>>>(qk, vt, attn);
    gemm_bt<1><<<dim3(64, 8), 256, 0, stream>>>(attn, wot, bo, out, nullptr, 8192, 1024, 1024, 1024);
}